// Round 1
// baseline (2852.073 us; speedup 1.0000x reference)
//
#include <hip/hip_runtime.h>
#include <math.h>

#define N_NODES 100000
#define N_EDGES 500000
#define N_PATHS 3
#define DIM 128
#define K_LAYERS 10

// ---------------- degree histogram ----------------
__global__ __launch_bounds__(256) void deg_kernel(const int* __restrict__ src,
                                                  const int* __restrict__ dst,
                                                  int* __restrict__ degS,
                                                  int* __restrict__ degD) {
    int e = blockIdx.x * 256 + threadIdx.x;
    if (e < N_EDGES) {
        atomicAdd(&degS[src[e]], 1);
        atomicAdd(&degD[dst[e]], 1);
    }
}

// ---------------- normalization factors ----------------
__global__ __launch_bounds__(256) void norm_kernel(const int* __restrict__ degS,
                                                   const int* __restrict__ degD,
                                                   float* __restrict__ norm_s,
                                                   float* __restrict__ norm_d) {
    int n = blockIdx.x * 256 + threadIdx.x;
    if (n < N_NODES) {
        norm_s[n] = 1.0f / sqrtf(fmaxf((float)degS[n], 1.0f));
        norm_d[n] = 1.0f / sqrtf(fmaxf((float)degD[n], 1.0f));
    }
}

// ---------------- exclusive scan of in-degrees (single block) ----------------
__global__ __launch_bounds__(1024) void scan_kernel(const int* __restrict__ cnt,
                                                    int* __restrict__ row_ptr,
                                                    int* __restrict__ cursor) {
    __shared__ int sums[1024];
    const int n = N_NODES;
    int t = threadIdx.x;
    int chunk = (n + 1023) / 1024;
    int beg = t * chunk;
    int end = min(beg + chunk, n);
    int s = 0;
    for (int i = beg; i < end; ++i) s += cnt[i];
    sums[t] = s;
    __syncthreads();
    // Kogge-Stone inclusive scan over 1024 partials
    for (int off = 1; off < 1024; off <<= 1) {
        int v = sums[t];
        int add = (t >= off) ? sums[t - off] : 0;
        __syncthreads();
        sums[t] = v + add;
        __syncthreads();
    }
    int prefix = (t == 0) ? 0 : sums[t - 1];
    for (int i = beg; i < end; ++i) {
        row_ptr[i] = prefix;
        cursor[i]  = prefix;
        prefix += cnt[i];
    }
    if (t == 1023) row_ptr[n] = sums[1023];
}

// ---------------- fill CSR (col=src, weight=norm_s[src]*norm_d[dst]) ----------------
__global__ __launch_bounds__(256) void fill_kernel(const int* __restrict__ src,
                                                   const int* __restrict__ dst,
                                                   const float* __restrict__ norm_s,
                                                   const float* __restrict__ norm_d,
                                                   int* __restrict__ cursor,
                                                   int2* __restrict__ cw) {
    int e = blockIdx.x * 256 + threadIdx.x;
    if (e < N_EDGES) {
        int s = src[e], d = dst[e];
        int pos = atomicAdd(&cursor[d], 1);
        float w = norm_s[s] * norm_d[d];
        cw[pos] = make_int2(s, __float_as_int(w));
    }
}

// ---------------- one APPNP layer: pure gather per dst node ----------------
// 32-lane group per node; lane owns a float4 (128 floats per row = 32 * float4)
__global__ __launch_bounds__(256) void prop_kernel(const float4* __restrict__ xsrc,
                                                   const float4* __restrict__ h0,
                                                   float4* __restrict__ xdst,
                                                   const int* __restrict__ row_ptr,
                                                   const int2* __restrict__ cw) {
    int node = blockIdx.x * 8 + (threadIdx.x >> 5);
    int lane = threadIdx.x & 31;
    if (node >= N_NODES) return;
    int beg = row_ptr[node];
    int end = row_ptr[node + 1];
    float ax = 0.f, ay = 0.f, az = 0.f, aw = 0.f;
    for (int i = beg; i < end; ++i) {
        int2 e = cw[i];
        float w = __int_as_float(e.y);
        float4 v = xsrc[(size_t)e.x * 32 + lane];
        ax = fmaf(w, v.x, ax);
        ay = fmaf(w, v.y, ay);
        az = fmaf(w, v.z, az);
        aw = fmaf(w, v.w, aw);
    }
    float4 h = h0[(size_t)node * 32 + lane];
    float4 o;
    o.x = 0.9f * ax + 0.1f * h.x;
    o.y = 0.9f * ay + 0.1f * h.y;
    o.z = 0.9f * az + 0.1f * h.z;
    o.w = 0.9f * aw + 0.1f * h.w;
    xdst[(size_t)node * 32 + lane] = o;
}

// ---------------- attention logits: wsum[p] += sum_n tanh(z_row@W1+b1)@w2 ----------------
// W1 (128x128 f32 = 64KB) in LDS; 4 rows per wave, lane computes cols (lane, lane+64)
__global__ __launch_bounds__(256) void attn_kernel(const float* __restrict__ z,
                                                   const float* __restrict__ W1,
                                                   const float* __restrict__ b1,
                                                   const float* __restrict__ w2,
                                                   float* __restrict__ wsum) {
    __shared__ float W1s[DIM * DIM];
    for (int i = threadIdx.x; i < DIM * DIM; i += 256) W1s[i] = W1[i];
    __syncthreads();

    int wid  = threadIdx.x >> 6;
    int lane = threadIdx.x & 63;
    float bias0 = b1[lane], bias1 = b1[lane + 64];
    float wA = w2[lane], wB = w2[lane + 64];
    float acc0 = 0.f, acc1 = 0.f, acc2 = 0.f;
    const int ROWS = N_PATHS * N_NODES;  // 300000, divisible by 4; path size divisible by 4

    for (int r0 = (blockIdx.x * 4 + wid) * 4; r0 < ROWS; r0 += gridDim.x * 16) {
        float d0a = 0.f, d0b = 0.f, d1a = 0.f, d1b = 0.f;
        float d2a = 0.f, d2b = 0.f, d3a = 0.f, d3b = 0.f;
        const float* zr = z + (size_t)r0 * DIM;
        for (int k = 0; k < DIM; k += 4) {
            float4 z0 = *(const float4*)(zr + k);
            float4 z1 = *(const float4*)(zr + DIM + k);
            float4 z2 = *(const float4*)(zr + 2 * DIM + k);
            float4 z3 = *(const float4*)(zr + 3 * DIM + k);
#pragma unroll
            for (int kk = 0; kk < 4; ++kk) {
                float w0 = W1s[(k + kk) * DIM + lane];
                float w1 = W1s[(k + kk) * DIM + 64 + lane];
                float z0k = (kk == 0) ? z0.x : (kk == 1) ? z0.y : (kk == 2) ? z0.z : z0.w;
                float z1k = (kk == 0) ? z1.x : (kk == 1) ? z1.y : (kk == 2) ? z1.z : z1.w;
                float z2k = (kk == 0) ? z2.x : (kk == 1) ? z2.y : (kk == 2) ? z2.z : z2.w;
                float z3k = (kk == 0) ? z3.x : (kk == 1) ? z3.y : (kk == 2) ? z3.z : z3.w;
                d0a = fmaf(z0k, w0, d0a); d0b = fmaf(z0k, w1, d0b);
                d1a = fmaf(z1k, w0, d1a); d1b = fmaf(z1k, w1, d1b);
                d2a = fmaf(z2k, w0, d2a); d2b = fmaf(z2k, w1, d2b);
                d3a = fmaf(z3k, w0, d3a); d3b = fmaf(z3k, w1, d3b);
            }
        }
        float t0 = tanhf(d0a + bias0) * wA + tanhf(d0b + bias1) * wB;
        float t1 = tanhf(d1a + bias0) * wA + tanhf(d1b + bias1) * wB;
        float t2 = tanhf(d2a + bias0) * wA + tanhf(d2b + bias1) * wB;
        float t3 = tanhf(d3a + bias0) * wA + tanhf(d3b + bias1) * wB;
#pragma unroll
        for (int off = 32; off; off >>= 1) {
            t0 += __shfl_xor(t0, off);
            t1 += __shfl_xor(t1, off);
            t2 += __shfl_xor(t2, off);
            t3 += __shfl_xor(t3, off);
        }
        float tsum = t0 + t1 + t2 + t3;
        int p = r0 / N_NODES;  // all 4 rows in same path (100000 % 4 == 0)
        if (p == 0) acc0 += tsum;
        else if (p == 1) acc1 += tsum;
        else acc2 += tsum;
    }
    if (lane == 0) {
        atomicAdd(&wsum[0], acc0);
        atomicAdd(&wsum[1], acc1);
        atomicAdd(&wsum[2], acc2);
    }
}

// ---------------- beta = softmax(wsum / N) over 3 paths ----------------
__global__ void beta_kernel(const float* __restrict__ wsum, float* __restrict__ beta) {
    if (threadIdx.x == 0 && blockIdx.x == 0) {
        float w0 = wsum[0] * (1.0f / N_NODES);
        float w1 = wsum[1] * (1.0f / N_NODES);
        float w2v = wsum[2] * (1.0f / N_NODES);
        float m = fmaxf(w0, fmaxf(w1, w2v));
        float e0 = expf(w0 - m), e1 = expf(w1 - m), e2 = expf(w2v - m);
        float inv = 1.0f / (e0 + e1 + e2);
        beta[0] = e0 * inv;
        beta[1] = e1 * inv;
        beta[2] = e2 * inv;
    }
}

// ---------------- out[n,:] = sum_p beta[p] * z[p,n,:] ----------------
__global__ __launch_bounds__(256) void combine_kernel(const float4* __restrict__ z4,
                                                      const float* __restrict__ beta,
                                                      float4* __restrict__ out4) {
    size_t idx = (size_t)blockIdx.x * 256 + threadIdx.x;
    const size_t M = (size_t)N_NODES * 32;
    if (idx < M) {
        float b0 = beta[0], b1 = beta[1], b2 = beta[2];
        float4 a = z4[idx];
        float4 b = z4[M + idx];
        float4 c = z4[2 * M + idx];
        float4 o;
        o.x = b0 * a.x + b1 * b.x + b2 * c.x;
        o.y = b0 * a.y + b1 * b.y + b2 * c.y;
        o.z = b0 * a.z + b1 * b.z + b2 * c.z;
        o.w = b0 * a.w + b1 * b.w + b2 * c.w;
        out4[idx] = o;
    }
}

extern "C" void kernel_launch(void* const* d_in, const int* in_sizes, int n_in,
                              void* d_out, int out_size, void* d_ws, size_t ws_size,
                              hipStream_t stream) {
    const float* h     = (const float*)d_in[0];
    const int*   edges = (const int*)d_in[1];   // (3, 2, 500000) int32
    const float* W1    = (const float*)d_in[2];
    const float* b1    = (const float*)d_in[3];
    const float* w2    = (const float*)d_in[4];
    float* out = (float*)d_out;

    // ---- workspace carve (all offsets kept 8B-aligned) ----
    char* ws = (char*)d_ws;
    float* z = (float*)ws;              ws += (size_t)N_PATHS * N_NODES * DIM * 4;  // 153.6 MB
    float* xb = (float*)ws;             ws += (size_t)N_NODES * DIM * 4;            // 51.2 MB
    int* row_ptr = (int*)ws;            ws += (size_t)(N_NODES + 2) * 4;            // padded for alignment
    int* cursor = (int*)ws;             ws += (size_t)N_NODES * 4;
    float* norm_s = (float*)ws;         ws += (size_t)N_NODES * 4;
    float* norm_d = (float*)ws;         ws += (size_t)N_NODES * 4;
    int2* cw = (int2*)ws;               ws += (size_t)N_EDGES * 8;                  // packed (col, weight)
    int* degS = (int*)ws;               ws += (size_t)N_NODES * 4;
    int* degD = (int*)ws;               ws += (size_t)N_NODES * 4;                  // adjacent to degS
    float* wsum = (float*)ws;           ws += 4 * 4;
    float* beta = (float*)ws;           ws += 4 * 4;

    for (int p = 0; p < N_PATHS; ++p) {
        const int* src = edges + (size_t)p * 2 * N_EDGES;
        const int* dst = src + N_EDGES;

        hipMemsetAsync(degS, 0, (size_t)2 * N_NODES * 4, stream);  // degS+degD together
        deg_kernel<<<(N_EDGES + 255) / 256, 256, 0, stream>>>(src, dst, degS, degD);
        norm_kernel<<<(N_NODES + 255) / 256, 256, 0, stream>>>(degS, degD, norm_s, norm_d);
        scan_kernel<<<1, 1024, 0, stream>>>(degD, row_ptr, cursor);
        fill_kernel<<<(N_EDGES + 255) / 256, 256, 0, stream>>>(src, dst, norm_s, norm_d, cursor, cw);

        float* zp = z + (size_t)p * N_NODES * DIM;
        for (int i = 0; i < K_LAYERS; ++i) {
            // i even -> write xb, i odd -> write zp; layer 9 (last) lands in zp
            const float* s = (i == 0) ? h : ((i & 1) ? xb : zp);
            float* dbuf = (i & 1) ? zp : xb;
            prop_kernel<<<(N_NODES + 7) / 8, 256, 0, stream>>>(
                (const float4*)s, (const float4*)h, (float4*)dbuf, row_ptr, cw);
        }
    }

    hipMemsetAsync(wsum, 0, 3 * 4, stream);
    attn_kernel<<<512, 256, 0, stream>>>(z, W1, b1, w2, wsum);
    beta_kernel<<<1, 64, 0, stream>>>(wsum, beta);
    combine_kernel<<<(N_NODES * 32 + 255) / 256, 256, 0, stream>>>(
        (const float4*)z, beta, (float4*)out);
}